// Round 1
// baseline (1876.831 us; speedup 1.0000x reference)
//
#include <hip/hip_runtime.h>
#include <hip/hip_bf16.h>

// GroupQuantLinear: y[m,n] = sum_k x[m,k] * (q[n,k]*s[n,g]+b[n,g]) + bias[n]
// M=4096, N=16384, K=4096, G=16 (group = 256 K-elems), 4-bit nibbles, 4/int32 word.
// Fused bf16-MFMA GEMM, 128x128 tile, BK=64, 4 waves (2x2), 4x4 16x16x32 frags/wave.
// Both operands reg-staged into XOR-swizzled LDS (byte ^= (row&7)<<4) since both
// need transformation (fp32->bf16 cvt / nibble dequant) -> global_load_lds N/A.

typedef short bf16x8 __attribute__((ext_vector_type(8)));
typedef float f32x4 __attribute__((ext_vector_type(4)));
typedef unsigned short u16;
typedef unsigned short u16x4 __attribute__((ext_vector_type(4)));
typedef unsigned short u16x8 __attribute__((ext_vector_type(8)));

#define BM 128
#define BN 128
#define BK 64
#define THREADS 256

static __device__ __forceinline__ u16 f2bf(float f) {
    __hip_bfloat16 h = __float2bfloat16(f);
    return __builtin_bit_cast(u16, h);
}

__global__ __launch_bounds__(THREADS, 2)
void gql_gemm(const float* __restrict__ A,    // [M][K] fp32
              const int* __restrict__ Wp,     // [N][K/4] packed nibbles
              const float* __restrict__ Ws,   // [N][G] scale
              const float* __restrict__ Wb,   // [N][G] bias (dequant)
              const float* __restrict__ Bias, // [N]
              float* __restrict__ Out,        // [M][N]
              int M, int N, int K, int G, int gshift)
{
    __shared__ __align__(16) u16 sA[BM * BK];  // 16 KB, row stride 128B, XOR-swizzled
    __shared__ __align__(16) u16 sB[BN * BK];  // 16 KB

    const int tid  = threadIdx.x;
    const int lane = tid & 63;
    const int wid  = tid >> 6;

    // XCD-bijective block swizzle (nwg % 8 == 0 here), then m-major so
    // consecutive wg share the A-panel (L2 locality).
    const int nwg = gridDim.x;
    int wg = blockIdx.x;
    if ((nwg & 7) == 0) wg = (wg & 7) * (nwg >> 3) + (wg >> 3);
    const int nt     = N / BN;
    const int tile_m = wg / nt;
    const int tile_n = wg % nt;
    const int m0 = tile_m * BM;
    const int n0 = tile_n * BN;

    const int wpr = K >> 2;  // int32 words per weight row

    // A staging: 8 iters; 16 threads/row, one float4 each (coalesced 256B/row-quarter)
    const int a_r = tid >> 4;          // 0..15
    const int a_c = (tid & 15) << 2;   // float col 0,4,...,60
    // B staging: 4 iters; 8 threads/row, 2 packed words each -> 8 bf16 -> one b128 write
    const int b_r = tid >> 3;          // 0..31
    const int b_w = (tid & 7) << 1;    // word 0,2,...,14

    // wave -> 64x64 output quadrant; 4x4 fragments of 16x16
    const int wr = (wid >> 1) << 6;
    const int wc = (wid & 1) << 6;
    const int fr = lane & 15;          // fragment row lane
    const int fq = lane >> 4;          // 0..3

    f32x4 acc[4][4] = {};

    for (int k0 = 0; k0 < K; k0 += BK) {
        __syncthreads();

        // ---- stage A tile: [128 rows][64 k] fp32 -> bf16, swizzled ----
        #pragma unroll
        for (int it = 0; it < 8; ++it) {
            const int row = it * 16 + a_r;
            const float4 v = *(const float4*)(A + (size_t)(m0 + row) * K + (k0 + a_c));
            u16x4 h;
            h[0] = f2bf(v.x); h[1] = f2bf(v.y); h[2] = f2bf(v.z); h[3] = f2bf(v.w);
            const int byte = (a_c << 1) ^ ((row & 7) << 4);
            *(u16x4*)((char*)sA + row * (BK * 2) + byte) = h;
        }

        // ---- stage B tile: [128 rows][16 words] -> dequant bf16, swizzled ----
        const int g = k0 >> gshift;    // BK=64 < group=256, so one group per step
        #pragma unroll
        for (int it = 0; it < 4; ++it) {
            const int row = it * 32 + b_r;
            const int gn  = n0 + row;
            const int2 w2 = *(const int2*)(Wp + (size_t)gn * wpr + (k0 >> 2) + b_w);
            const float s = Ws[gn * G + g];
            const float b = Wb[gn * G + g];
            u16x8 h;
            #pragma unroll
            for (int j = 0; j < 4; ++j)
                h[j]     = f2bf(fmaf((float)((w2.x >> (4 * j)) & 0xF), s, b));
            #pragma unroll
            for (int j = 0; j < 4; ++j)
                h[4 + j] = f2bf(fmaf((float)((w2.y >> (4 * j)) & 0xF), s, b));
            const int byte = (b_w << 3) ^ ((row & 7) << 4);
            *(u16x8*)((char*)sB + row * (BK * 2) + byte) = h;
        }

        __syncthreads();

        // ---- compute: 2 K-substeps of 32 ----
        #pragma unroll
        for (int sub = 0; sub < 2; ++sub) {
            const int kch = (sub << 2) + fq;   // 16B chunk index 0..7 within row
            bf16x8 af[4], bfg[4];
            #pragma unroll
            for (int i = 0; i < 4; ++i) {
                const int row = wr + i * 16 + fr;
                af[i] = *(const bf16x8*)((const char*)sA + row * (BK * 2)
                                         + ((kch << 4) ^ ((row & 7) << 4)));
            }
            #pragma unroll
            for (int j = 0; j < 4; ++j) {
                const int row = wc + j * 16 + fr;
                bfg[j] = *(const bf16x8*)((const char*)sB + row * (BK * 2)
                                          + ((kch << 4) ^ ((row & 7) << 4)));
            }
            #pragma unroll
            for (int i = 0; i < 4; ++i)
                #pragma unroll
                for (int j = 0; j < 4; ++j)
                    acc[i][j] = __builtin_amdgcn_mfma_f32_16x16x32_bf16(
                        af[i], bfg[j], acc[i][j], 0, 0, 0);
        }
    }

    // ---- epilogue: D row = 4*(lane>>4)+reg, col = lane&15 ----
    #pragma unroll
    for (int j = 0; j < 4; ++j) {
        const int n = n0 + wc + j * 16 + fr;
        const float bv = Bias[n];
        #pragma unroll
        for (int i = 0; i < 4; ++i) {
            const int mb = m0 + wr + i * 16 + (fq << 2);
            #pragma unroll
            for (int r = 0; r < 4; ++r)
                Out[(size_t)(mb + r) * N + n] = acc[i][j][r] + bv;
        }
    }
}

extern "C" void kernel_launch(void* const* d_in, const int* in_sizes, int n_in,
                              void* d_out, int out_size, void* d_ws, size_t ws_size,
                              hipStream_t stream) {
    const float* A    = (const float*)d_in[0];
    const int*   Wp   = (const int*)d_in[1];
    const float* Ws   = (const float*)d_in[2];
    const float* Wb   = (const float*)d_in[3];
    const float* Bias = (const float*)d_in[4];
    float* Out = (float*)d_out;

    const int OUT  = in_sizes[4];
    const int OG   = in_sizes[2];          // OUT * G
    const int G    = OG / OUT;             // 16
    const int cols = in_sizes[1] / OG;     // 64
    const int IN   = G * cols * 4;         // 4096
    const int M    = in_sizes[0] / IN;     // 4096

    const int gk = IN / G;                 // 256
    int gshift = 0;
    while ((1 << gshift) < gk) ++gshift;   // 8

    dim3 grid((M / BM) * (OUT / BN));
    gql_gemm<<<grid, THREADS, 0, stream>>>(A, Wp, Ws, Wb, Bias, Out,
                                           M, OUT, IN, G, gshift);
}

// Round 2
// 686.864 us; speedup vs baseline: 2.7325x; 2.7325x over previous
//
#include <hip/hip_runtime.h>
#include <hip/hip_bf16.h>

// GroupQuantLinear: y[m,n] = sum_k x[m,k] * (q[n,k]*s[n,g]+b[n,g]) + bias[n]
// M=4096, N=16384, K=4096, G=16 (group=256 K), 4-bit nibbles, 4 per int32 word.
//
// Round 2: predecode-to-ws path (if ws_size fits):
//   1) cvtA:  fp32 A -> bf16 wsA [M][K]           (~16 us, mem-bound)
//   2) deqW:  packed W -> bf16 wsW [N][K]         (~32 us, mem-bound)
//   3) gql_gemm_pre: pure bf16 GEMM, m97 structure: global_load_lds(16B)
//      with pre-swizzled per-lane global source, linear LDS dest,
//      XOR-swizzled ds_read_b128 (conflict-free), 128x128xBK64, 4 waves.
// Fallback (ws too small): round-1 fused kernel, unmodified (validated).

typedef short bf16x8 __attribute__((ext_vector_type(8)));
typedef float f32x4 __attribute__((ext_vector_type(4)));
typedef unsigned short u16;
typedef unsigned short u16x4 __attribute__((ext_vector_type(4)));
typedef unsigned short u16x8 __attribute__((ext_vector_type(8)));

#define BM 128
#define BN 128
#define BK 64
#define THREADS 256

static __device__ __forceinline__ u16 f2bf(float f) {
    __hip_bfloat16 h = __float2bfloat16(f);
    return __builtin_bit_cast(u16, h);
}

// ---------------- predecode kernels ----------------

__global__ void cvtA_kernel(const float* __restrict__ A, u16* __restrict__ wsA,
                            size_t n8) {
    size_t i = (size_t)blockIdx.x * blockDim.x + threadIdx.x;
    if (i >= n8) return;
    const float4 v0 = *(const float4*)(A + i * 8);
    const float4 v1 = *(const float4*)(A + i * 8 + 4);
    u16x8 h;
    h[0] = f2bf(v0.x); h[1] = f2bf(v0.y); h[2] = f2bf(v0.z); h[3] = f2bf(v0.w);
    h[4] = f2bf(v1.x); h[5] = f2bf(v1.y); h[6] = f2bf(v1.z); h[7] = f2bf(v1.w);
    *(u16x8*)(wsA + i * 8) = h;
}

__global__ void deqW_kernel(const int* __restrict__ Wp, const float* __restrict__ Ws,
                            const float* __restrict__ Wb, u16* __restrict__ wsW,
                            int K, int G, int gshift, int kgshift, size_t n8) {
    size_t t = (size_t)blockIdx.x * blockDim.x + threadIdx.x;
    if (t >= n8) return;
    const int n  = (int)(t >> kgshift);           // row
    const int kg = (int)(t & ((1u << kgshift) - 1));
    const int k  = kg << 3;                        // 8 k-elements per thread
    const int g  = k >> gshift;
    const float s = Ws[n * G + g];
    const float b = Wb[n * G + g];
    const int2 w2 = *(const int2*)(Wp + (size_t)n * (K >> 2) + (k >> 2));
    u16x8 h;
    #pragma unroll
    for (int j = 0; j < 4; ++j)
        h[j]     = f2bf(fmaf((float)((w2.x >> (4 * j)) & 0xF), s, b));
    #pragma unroll
    for (int j = 0; j < 4; ++j)
        h[4 + j] = f2bf(fmaf((float)((w2.y >> (4 * j)) & 0xF), s, b));
    *(u16x8*)(wsW + ((size_t)n << (kgshift + 3)) + k) = h;
}

// ---------------- predecoded bf16 GEMM (m97 structure) ----------------

__global__ __launch_bounds__(THREADS, 2)
void gql_gemm_pre(const u16* __restrict__ wsA,  // [M][K] bf16
                  const u16* __restrict__ wsW,  // [N][K] bf16
                  const float* __restrict__ Bias,
                  float* __restrict__ Out,      // [M][N] fp32
                  int M, int N, int K)
{
    __shared__ __align__(16) u16 sA[BM * BK];  // 16 KB, linear [row][64]
    __shared__ __align__(16) u16 sB[BN * BK];  // 16 KB

    const int tid  = threadIdx.x;
    const int lane = tid & 63;
    const int wid  = tid >> 6;

    const int nwg = gridDim.x;
    int wg = blockIdx.x;
    if ((nwg & 7) == 0) wg = (wg & 7) * (nwg >> 3) + (wg >> 3);
    const int nt     = N / BN;
    const int tile_m = wg / nt;
    const int tile_n = wg % nt;
    const int m0 = tile_m * BM;
    const int n0 = tile_n * BN;

    // staging geometry: per global_load_lds inst a wave writes 64 lanes x 16B
    // = 8 rows x 64 bf16, linear in LDS. Per-lane global source carries the
    // inverse XOR so that ds_read with the same XOR is conflict-free.
    const int st_r  = (lane >> 3);   // 0..7 row within 8-row chunk
    const int st_g  = lane & 7;      // granule slot 0..7 (8 bf16 = 16B)

    const int wr = (wid >> 1) << 6;
    const int wc = (wid & 1) << 6;
    const int fr = lane & 15;
    const int fq = lane >> 4;

    f32x4 acc[4][4] = {};

    for (int k0 = 0; k0 < K; k0 += BK) {
        __syncthreads();

        #pragma unroll
        for (int i = 0; i < 4; ++i) {
            const int r = wid * 32 + i * 8 + st_r;   // tile row 0..127
            const int gsrc = (st_g ^ (r & 7)) << 3;  // pre-swizzled k offset
            const u16* srcA = wsA + (size_t)(m0 + r) * K + k0 + gsrc;
            const u16* srcB = wsW + (size_t)(n0 + r) * K + k0 + gsrc;
            __builtin_amdgcn_global_load_lds(
                (const __attribute__((address_space(1))) void*)srcA,
                (__attribute__((address_space(3))) void*)&sA[(wid * 32 + i * 8) * BK],
                16, 0, 0);
            __builtin_amdgcn_global_load_lds(
                (const __attribute__((address_space(1))) void*)srcB,
                (__attribute__((address_space(3))) void*)&sB[(wid * 32 + i * 8) * BK],
                16, 0, 0);
        }

        __syncthreads();

        #pragma unroll
        for (int sub = 0; sub < 2; ++sub) {
            const int kch = (sub << 2) + fq;
            bf16x8 af[4], bfg[4];
            #pragma unroll
            for (int i = 0; i < 4; ++i) {
                const int row = wr + i * 16 + fr;
                af[i] = *(const bf16x8*)((const char*)sA + row * (BK * 2)
                                         + (((kch ^ (row & 7)) << 4)));
            }
            #pragma unroll
            for (int j = 0; j < 4; ++j) {
                const int row = wc + j * 16 + fr;
                bfg[j] = *(const bf16x8*)((const char*)sB + row * (BK * 2)
                                          + (((kch ^ (row & 7)) << 4)));
            }
            #pragma unroll
            for (int i = 0; i < 4; ++i)
                #pragma unroll
                for (int j = 0; j < 4; ++j)
                    acc[i][j] = __builtin_amdgcn_mfma_f32_16x16x32_bf16(
                        af[i], bfg[j], acc[i][j], 0, 0, 0);
        }
    }

    #pragma unroll
    for (int j = 0; j < 4; ++j) {
        const int n = n0 + wc + j * 16 + fr;
        const float bv = Bias[n];
        #pragma unroll
        for (int i = 0; i < 4; ++i) {
            const int mb = m0 + wr + i * 16 + (fq << 2);
            #pragma unroll
            for (int r = 0; r < 4; ++r)
                Out[(size_t)(mb + r) * N + n] = acc[i][j][r] + bv;
        }
    }
}

// ---------------- round-1 fused fallback (validated) ----------------

__global__ __launch_bounds__(THREADS, 2)
void gql_gemm(const float* __restrict__ A,
              const int* __restrict__ Wp,
              const float* __restrict__ Ws,
              const float* __restrict__ Wb,
              const float* __restrict__ Bias,
              float* __restrict__ Out,
              int M, int N, int K, int G, int gshift)
{
    __shared__ __align__(16) u16 sA[BM * BK];
    __shared__ __align__(16) u16 sB[BN * BK];

    const int tid  = threadIdx.x;
    const int lane = tid & 63;
    const int wid  = tid >> 6;

    const int nwg = gridDim.x;
    int wg = blockIdx.x;
    if ((nwg & 7) == 0) wg = (wg & 7) * (nwg >> 3) + (wg >> 3);
    const int nt     = N / BN;
    const int tile_m = wg / nt;
    const int tile_n = wg % nt;
    const int m0 = tile_m * BM;
    const int n0 = tile_n * BN;

    const int wpr = K >> 2;

    const int a_r = tid >> 4;
    const int a_c = (tid & 15) << 2;
    const int b_r = tid >> 3;
    const int b_w = (tid & 7) << 1;

    const int wr = (wid >> 1) << 6;
    const int wc = (wid & 1) << 6;
    const int fr = lane & 15;
    const int fq = lane >> 4;

    f32x4 acc[4][4] = {};

    for (int k0 = 0; k0 < K; k0 += BK) {
        __syncthreads();

        #pragma unroll
        for (int it = 0; it < 8; ++it) {
            const int row = it * 16 + a_r;
            const float4 v = *(const float4*)(A + (size_t)(m0 + row) * K + (k0 + a_c));
            u16x4 h;
            h[0] = f2bf(v.x); h[1] = f2bf(v.y); h[2] = f2bf(v.z); h[3] = f2bf(v.w);
            const int byte = (a_c << 1) ^ ((row & 7) << 4);
            *(u16x4*)((char*)sA + row * (BK * 2) + byte) = h;
        }

        const int g = k0 >> gshift;
        #pragma unroll
        for (int it = 0; it < 4; ++it) {
            const int row = it * 32 + b_r;
            const int gn  = n0 + row;
            const int2 w2 = *(const int2*)(Wp + (size_t)gn * wpr + (k0 >> 2) + b_w);
            const float s = Ws[gn * G + g];
            const float b = Wb[gn * G + g];
            u16x8 h;
            #pragma unroll
            for (int j = 0; j < 4; ++j)
                h[j]     = f2bf(fmaf((float)((w2.x >> (4 * j)) & 0xF), s, b));
            #pragma unroll
            for (int j = 0; j < 4; ++j)
                h[4 + j] = f2bf(fmaf((float)((w2.y >> (4 * j)) & 0xF), s, b));
            const int byte = (b_w << 3) ^ ((row & 7) << 4);
            *(u16x8*)((char*)sB + row * (BK * 2) + byte) = h;
        }

        __syncthreads();

        #pragma unroll
        for (int sub = 0; sub < 2; ++sub) {
            const int kch = (sub << 2) + fq;
            bf16x8 af[4], bfg[4];
            #pragma unroll
            for (int i = 0; i < 4; ++i) {
                const int row = wr + i * 16 + fr;
                af[i] = *(const bf16x8*)((const char*)sA + row * (BK * 2)
                                         + ((kch << 4) ^ ((row & 7) << 4)));
            }
            #pragma unroll
            for (int j = 0; j < 4; ++j) {
                const int row = wc + j * 16 + fr;
                bfg[j] = *(const bf16x8*)((const char*)sB + row * (BK * 2)
                                          + ((kch << 4) ^ ((row & 7) << 4)));
            }
            #pragma unroll
            for (int i = 0; i < 4; ++i)
                #pragma unroll
                for (int j = 0; j < 4; ++j)
                    acc[i][j] = __builtin_amdgcn_mfma_f32_16x16x32_bf16(
                        af[i], bfg[j], acc[i][j], 0, 0, 0);
        }
    }

    #pragma unroll
    for (int j = 0; j < 4; ++j) {
        const int n = n0 + wc + j * 16 + fr;
        const float bv = Bias[n];
        #pragma unroll
        for (int i = 0; i < 4; ++i) {
            const int mb = m0 + wr + i * 16 + (fq << 2);
            #pragma unroll
            for (int r = 0; r < 4; ++r)
                Out[(size_t)(mb + r) * N + n] = acc[i][j][r] + bv;
        }
    }
}

extern "C" void kernel_launch(void* const* d_in, const int* in_sizes, int n_in,
                              void* d_out, int out_size, void* d_ws, size_t ws_size,
                              hipStream_t stream) {
    const float* A    = (const float*)d_in[0];
    const int*   Wp   = (const int*)d_in[1];
    const float* Ws   = (const float*)d_in[2];
    const float* Wb   = (const float*)d_in[3];
    const float* Bias = (const float*)d_in[4];
    float* Out = (float*)d_out;

    const int OUT  = in_sizes[4];
    const int OG   = in_sizes[2];          // OUT * G
    const int G    = OG / OUT;             // 16
    const int cols = in_sizes[1] / OG;     // 64
    const int IN   = G * cols * 4;         // 4096
    const int M    = in_sizes[0] / IN;     // 4096

    const int gk = IN / G;                 // 256
    int gshift = 0;
    while ((1 << gshift) < gk) ++gshift;   // 8

    const size_t needA = (size_t)M * IN * 2;
    const size_t needW = (size_t)OUT * IN * 2;
    dim3 grid((M / BM) * (OUT / BN));

    if (ws_size >= needA + needW && (IN & 7) == 0) {
        u16* wsA = (u16*)d_ws;
        u16* wsW = (u16*)((char*)d_ws + needA);

        const size_t nA8 = (size_t)M * IN / 8;
        cvtA_kernel<<<(unsigned)((nA8 + 255) / 256), 256, 0, stream>>>(A, wsA, nA8);

        int kgshift = 0;
        while ((1 << kgshift) < (IN >> 3)) ++kgshift;  // log2(K/8) = 9
        const size_t nW8 = (size_t)OUT * IN / 8;
        deqW_kernel<<<(unsigned)((nW8 + 255) / 256), 256, 0, stream>>>(
            Wp, Ws, Wb, wsW, IN, G, gshift, kgshift, nW8);

        gql_gemm_pre<<<grid, THREADS, 0, stream>>>(wsA, wsW, Bias, Out, M, OUT, IN);
    } else {
        gql_gemm<<<grid, THREADS, 0, stream>>>(A, Wp, Ws, Wb, Bias, Out,
                                               M, OUT, IN, G, gshift);
    }
}

// Round 3
// 665.470 us; speedup vs baseline: 2.8203x; 1.0321x over previous
//
#include <hip/hip_runtime.h>
#include <hip/hip_bf16.h>

// GroupQuantLinear: y[m,n] = sum_k x[m,k] * (q[n,k]*s[n,g]+b[n,g]) + bias[n]
// M=4096, N=16384, K=4096, G=16, 4-bit nibbles packed 4/int32.
//
// Round 3: predecode (A->bf16, W->bf16 in d_ws) + 256x256 deep-pipelined GEMM:
//   512 thr / 8 waves (2Mx4N), BK=64, double-buffered 128KB LDS,
//   counted s_waitcnt vmcnt(8) + raw s_barrier (loads stay in flight across
//   barriers), setprio around MFMA clusters, XOR-swizzled LDS (validated).
// Fallbacks: round-2 128^2 kernel (validated) for 128-divisible shapes,
//            round-1 fused kernel if ws too small.

typedef short bf16x8 __attribute__((ext_vector_type(8)));
typedef float f32x4 __attribute__((ext_vector_type(4)));
typedef unsigned short u16;
typedef unsigned short u16x4 __attribute__((ext_vector_type(4)));
typedef unsigned short u16x8 __attribute__((ext_vector_type(8)));

#define BM 128
#define BN 128
#define BK 64
#define THREADS 256

#define BM2 256
#define BN2 256
#define BK2 64
#define THREADS2 512

static __device__ __forceinline__ u16 f2bf(float f) {
    __hip_bfloat16 h = __float2bfloat16(f);
    return __builtin_bit_cast(u16, h);
}

// ---------------- predecode kernels ----------------

__global__ void cvtA_kernel(const float* __restrict__ A, u16* __restrict__ wsA,
                            size_t n8) {
    size_t i = (size_t)blockIdx.x * blockDim.x + threadIdx.x;
    if (i >= n8) return;
    const float4 v0 = *(const float4*)(A + i * 8);
    const float4 v1 = *(const float4*)(A + i * 8 + 4);
    u16x8 h;
    h[0] = f2bf(v0.x); h[1] = f2bf(v0.y); h[2] = f2bf(v0.z); h[3] = f2bf(v0.w);
    h[4] = f2bf(v1.x); h[5] = f2bf(v1.y); h[6] = f2bf(v1.z); h[7] = f2bf(v1.w);
    *(u16x8*)(wsA + i * 8) = h;
}

__global__ void deqW_kernel(const int* __restrict__ Wp, const float* __restrict__ Ws,
                            const float* __restrict__ Wb, u16* __restrict__ wsW,
                            int K, int G, int gshift, int kgshift, size_t n8) {
    size_t t = (size_t)blockIdx.x * blockDim.x + threadIdx.x;
    if (t >= n8) return;
    const int n  = (int)(t >> kgshift);
    const int kg = (int)(t & ((1u << kgshift) - 1));
    const int k  = kg << 3;
    const int g  = k >> gshift;
    const float s = Ws[n * G + g];
    const float b = Wb[n * G + g];
    const int2 w2 = *(const int2*)(Wp + (size_t)n * (K >> 2) + (k >> 2));
    u16x8 h;
    #pragma unroll
    for (int j = 0; j < 4; ++j)
        h[j]     = f2bf(fmaf((float)((w2.x >> (4 * j)) & 0xF), s, b));
    #pragma unroll
    for (int j = 0; j < 4; ++j)
        h[4 + j] = f2bf(fmaf((float)((w2.y >> (4 * j)) & 0xF), s, b));
    *(u16x8*)(wsW + ((size_t)n << (kgshift + 3)) + k) = h;
}

// ---------------- 256x256 deep-pipelined bf16 GEMM ----------------

__global__ __launch_bounds__(THREADS2, 2)
void gql_gemm_256(const u16* __restrict__ wsA,  // [M][K] bf16
                  const u16* __restrict__ wsW,  // [N][K] bf16
                  const float* __restrict__ Bias,
                  float* __restrict__ Out,      // [M][N] fp32
                  int M, int N, int K)
{
    __shared__ __align__(16) u16 sA[2][BM2 * BK2];  // 2 x 32 KB
    __shared__ __align__(16) u16 sB[2][BN2 * BK2];  // 2 x 32 KB

    const int tid  = threadIdx.x;
    const int lane = tid & 63;
    const int wid  = tid >> 6;     // 0..7
    const int wm   = wid >> 2;     // 0..1 -> rows wm*128..+127
    const int wn   = wid & 3;      // 0..3 -> cols wn*64..+63

    const int nwg = gridDim.x;
    int wg = blockIdx.x;
    if ((nwg & 7) == 0) wg = (wg & 7) * (nwg >> 3) + (wg >> 3);
    const int nt = N / BN2;
    const int m0 = (wg / nt) * BM2;
    const int n0 = (wg % nt) * BN2;

    // staging: per statement a wave covers 8 rows x 64 k (64 lanes x 16B),
    // linear LDS dest; global source pre-swizzled so swizzled ds_read is
    // conflict-free (validated in round 2, SQ_LDS_BANK_CONFLICT = 0).
    const int st_row = wid * 8 + (lane >> 3);               // 0..63 within chunk
    const int gsrc   = ((lane & 7) ^ (lane >> 3)) << 3;     // k-elem offset

    const int fr = lane & 15;
    const int fq = lane >> 4;

    f32x4 acc[8][4] = {};

    const int NT = K / BK2;

    auto stage = [&](int t, int buf) {
        const int k0 = t * BK2;
        #pragma unroll
        for (int s = 0; s < 4; ++s) {
            const int r = s * 64 + st_row;
            const u16* srcA = wsA + (size_t)(m0 + r) * K + k0 + gsrc;
            __builtin_amdgcn_global_load_lds(
                (const __attribute__((address_space(1))) void*)srcA,
                (__attribute__((address_space(3))) void*)&sA[buf][(s * 64 + wid * 8) * BK2],
                16, 0, 0);
            const u16* srcB = wsW + (size_t)(n0 + r) * K + k0 + gsrc;
            __builtin_amdgcn_global_load_lds(
                (const __attribute__((address_space(1))) void*)srcB,
                (__attribute__((address_space(3))) void*)&sB[buf][(s * 64 + wid * 8) * BK2],
                16, 0, 0);
        }
    };

    auto compute = [&](int buf) {
        #pragma unroll
        for (int ks = 0; ks < 2; ++ks) {
            const int kx = ((((ks << 2) + fq) ^ (fr & 7)) << 4);  // byte in row
            bf16x8 af[8], bfg[4];
            #pragma unroll
            for (int i = 0; i < 8; ++i) {
                const int row = wm * 128 + i * 16 + fr;
                af[i] = *(const bf16x8*)((const char*)&sA[buf][0]
                                         + row * (BK2 * 2) + kx);
            }
            #pragma unroll
            for (int j = 0; j < 4; ++j) {
                const int row = wn * 64 + j * 16 + fr;
                bfg[j] = *(const bf16x8*)((const char*)&sB[buf][0]
                                          + row * (BK2 * 2) + kx);
            }
            __builtin_amdgcn_s_setprio(1);
            #pragma unroll
            for (int i = 0; i < 8; ++i)
                #pragma unroll
                for (int j = 0; j < 4; ++j)
                    acc[i][j] = __builtin_amdgcn_mfma_f32_16x16x32_bf16(
                        af[i], bfg[j], acc[i][j], 0, 0, 0);
            __builtin_amdgcn_s_setprio(0);
        }
    };

    // prologue
    stage(0, 0);
    int cur = 0;

    for (int t = 0; t < NT - 1; ++t) {
        stage(t + 1, cur ^ 1);                 // overwrite buffer consumed at t-1
        __builtin_amdgcn_sched_barrier(0);
        asm volatile("s_waitcnt vmcnt(8)" ::: "memory");  // tile t landed; t+1 in flight
        __builtin_amdgcn_sched_barrier(0);
        __builtin_amdgcn_s_barrier();          // raw: no vmcnt drain
        asm volatile("" ::: "memory");
        compute(cur);
        __builtin_amdgcn_sched_barrier(0);
        asm volatile("" ::: "memory");
        __builtin_amdgcn_s_barrier();          // readers done before next overwrite
        asm volatile("" ::: "memory");
        cur ^= 1;
    }
    // tail tile
    asm volatile("s_waitcnt vmcnt(0)" ::: "memory");
    __builtin_amdgcn_s_barrier();
    asm volatile("" ::: "memory");
    compute(cur);

    // epilogue: D row = 4*fq + r (m), col = fr (n)
    #pragma unroll
    for (int j = 0; j < 4; ++j) {
        const int n = n0 + wn * 64 + j * 16 + fr;
        const float bv = Bias[n];
        #pragma unroll
        for (int i = 0; i < 8; ++i) {
            const int mb = m0 + wm * 128 + i * 16 + (fq << 2);
            #pragma unroll
            for (int r = 0; r < 4; ++r)
                Out[(size_t)(mb + r) * N + n] = acc[i][j][r] + bv;
        }
    }
}

// ---------------- round-2 128x128 kernel (validated fallback) ----------------

__global__ __launch_bounds__(THREADS, 2)
void gql_gemm_pre(const u16* __restrict__ wsA,
                  const u16* __restrict__ wsW,
                  const float* __restrict__ Bias,
                  float* __restrict__ Out,
                  int M, int N, int K)
{
    __shared__ __align__(16) u16 sA[BM * BK];
    __shared__ __align__(16) u16 sB[BN * BK];

    const int tid  = threadIdx.x;
    const int lane = tid & 63;
    const int wid  = tid >> 6;

    const int nwg = gridDim.x;
    int wg = blockIdx.x;
    if ((nwg & 7) == 0) wg = (wg & 7) * (nwg >> 3) + (wg >> 3);
    const int nt     = N / BN;
    const int m0 = (wg / nt) * BM;
    const int n0 = (wg % nt) * BN;

    const int st_r  = (lane >> 3);
    const int st_g  = lane & 7;

    const int wr = (wid >> 1) << 6;
    const int wc = (wid & 1) << 6;
    const int fr = lane & 15;
    const int fq = lane >> 4;

    f32x4 acc[4][4] = {};

    for (int k0 = 0; k0 < K; k0 += BK) {
        __syncthreads();

        #pragma unroll
        for (int i = 0; i < 4; ++i) {
            const int r = wid * 32 + i * 8 + st_r;
            const int gsrc = (st_g ^ (r & 7)) << 3;
            const u16* srcA = wsA + (size_t)(m0 + r) * K + k0 + gsrc;
            const u16* srcB = wsW + (size_t)(n0 + r) * K + k0 + gsrc;
            __builtin_amdgcn_global_load_lds(
                (const __attribute__((address_space(1))) void*)srcA,
                (__attribute__((address_space(3))) void*)&sA[(wid * 32 + i * 8) * BK],
                16, 0, 0);
            __builtin_amdgcn_global_load_lds(
                (const __attribute__((address_space(1))) void*)srcB,
                (__attribute__((address_space(3))) void*)&sB[(wid * 32 + i * 8) * BK],
                16, 0, 0);
        }

        __syncthreads();

        #pragma unroll
        for (int sub = 0; sub < 2; ++sub) {
            const int kch = (sub << 2) + fq;
            bf16x8 af[4], bfg[4];
            #pragma unroll
            for (int i = 0; i < 4; ++i) {
                const int row = wr + i * 16 + fr;
                af[i] = *(const bf16x8*)((const char*)sA + row * (BK * 2)
                                         + (((kch ^ (row & 7)) << 4)));
            }
            #pragma unroll
            for (int j = 0; j < 4; ++j) {
                const int row = wc + j * 16 + fr;
                bfg[j] = *(const bf16x8*)((const char*)sB + row * (BK * 2)
                                          + (((kch ^ (row & 7)) << 4)));
            }
            #pragma unroll
            for (int i = 0; i < 4; ++i)
                #pragma unroll
                for (int j = 0; j < 4; ++j)
                    acc[i][j] = __builtin_amdgcn_mfma_f32_16x16x32_bf16(
                        af[i], bfg[j], acc[i][j], 0, 0, 0);
        }
    }

    #pragma unroll
    for (int j = 0; j < 4; ++j) {
        const int n = n0 + wc + j * 16 + fr;
        const float bv = Bias[n];
        #pragma unroll
        for (int i = 0; i < 4; ++i) {
            const int mb = m0 + wr + i * 16 + (fq << 2);
            #pragma unroll
            for (int r = 0; r < 4; ++r)
                Out[(size_t)(mb + r) * N + n] = acc[i][j][r] + bv;
        }
    }
}

// ---------------- round-1 fused fallback ----------------

__global__ __launch_bounds__(THREADS, 2)
void gql_gemm(const float* __restrict__ A,
              const int* __restrict__ Wp,
              const float* __restrict__ Ws,
              const float* __restrict__ Wb,
              const float* __restrict__ Bias,
              float* __restrict__ Out,
              int M, int N, int K, int G, int gshift)
{
    __shared__ __align__(16) u16 sA[BM * BK];
    __shared__ __align__(16) u16 sB[BN * BK];

    const int tid  = threadIdx.x;
    const int lane = tid & 63;
    const int wid  = tid >> 6;

    const int nwg = gridDim.x;
    int wg = blockIdx.x;
    if ((nwg & 7) == 0) wg = (wg & 7) * (nwg >> 3) + (wg >> 3);
    const int nt     = N / BN;
    const int m0 = (wg / nt) * BM;
    const int n0 = (wg % nt) * BN;

    const int wpr = K >> 2;

    const int a_r = tid >> 4;
    const int a_c = (tid & 15) << 2;
    const int b_r = tid >> 3;
    const int b_w = (tid & 7) << 1;

    const int wr = (wid >> 1) << 6;
    const int wc = (wid & 1) << 6;
    const int fr = lane & 15;
    const int fq = lane >> 4;

    f32x4 acc[4][4] = {};

    for (int k0 = 0; k0 < K; k0 += BK) {
        __syncthreads();

        #pragma unroll
        for (int it = 0; it < 8; ++it) {
            const int row = it * 16 + a_r;
            const float4 v = *(const float4*)(A + (size_t)(m0 + row) * K + (k0 + a_c));
            u16x4 h;
            h[0] = f2bf(v.x); h[1] = f2bf(v.y); h[2] = f2bf(v.z); h[3] = f2bf(v.w);
            const int byte = (a_c << 1) ^ ((row & 7) << 4);
            *(u16x4*)((char*)sA + row * (BK * 2) + byte) = h;
        }

        const int g = k0 >> gshift;
        #pragma unroll
        for (int it = 0; it < 4; ++it) {
            const int row = it * 32 + b_r;
            const int gn  = n0 + row;
            const int2 w2 = *(const int2*)(Wp + (size_t)gn * wpr + (k0 >> 2) + b_w);
            const float s = Ws[gn * G + g];
            const float b = Wb[gn * G + g];
            u16x8 h;
            #pragma unroll
            for (int j = 0; j < 4; ++j)
                h[j]     = f2bf(fmaf((float)((w2.x >> (4 * j)) & 0xF), s, b));
            #pragma unroll
            for (int j = 0; j < 4; ++j)
                h[4 + j] = f2bf(fmaf((float)((w2.y >> (4 * j)) & 0xF), s, b));
            const int byte = (b_w << 3) ^ ((row & 7) << 4);
            *(u16x8*)((char*)sB + row * (BK * 2) + byte) = h;
        }

        __syncthreads();

        #pragma unroll
        for (int sub = 0; sub < 2; ++sub) {
            const int kch = (sub << 2) + fq;
            bf16x8 af[4], bfg[4];
            #pragma unroll
            for (int i = 0; i < 4; ++i) {
                const int row = wr + i * 16 + fr;
                af[i] = *(const bf16x8*)((const char*)sA + row * (BK * 2)
                                         + ((kch << 4) ^ ((row & 7) << 4)));
            }
            #pragma unroll
            for (int j = 0; j < 4; ++j) {
                const int row = wc + j * 16 + fr;
                bfg[j] = *(const bf16x8*)((const char*)sB + row * (BK * 2)
                                          + ((kch << 4) ^ ((row & 7) << 4)));
            }
            #pragma unroll
            for (int i = 0; i < 4; ++i)
                #pragma unroll
                for (int j = 0; j < 4; ++j)
                    acc[i][j] = __builtin_amdgcn_mfma_f32_16x16x32_bf16(
                        af[i], bfg[j], acc[i][j], 0, 0, 0);
        }
    }

    #pragma unroll
    for (int j = 0; j < 4; ++j) {
        const int n = n0 + wc + j * 16 + fr;
        const float bv = Bias[n];
        #pragma unroll
        for (int i = 0; i < 4; ++i) {
            const int mb = m0 + wr + i * 16 + (fq << 2);
            #pragma unroll
            for (int r = 0; r < 4; ++r)
                Out[(size_t)(mb + r) * N + n] = acc[i][j][r] + bv;
        }
    }
}

extern "C" void kernel_launch(void* const* d_in, const int* in_sizes, int n_in,
                              void* d_out, int out_size, void* d_ws, size_t ws_size,
                              hipStream_t stream) {
    const float* A    = (const float*)d_in[0];
    const int*   Wp   = (const int*)d_in[1];
    const float* Ws   = (const float*)d_in[2];
    const float* Wb   = (const float*)d_in[3];
    const float* Bias = (const float*)d_in[4];
    float* Out = (float*)d_out;

    const int OUT  = in_sizes[4];
    const int OG   = in_sizes[2];          // OUT * G
    const int G    = OG / OUT;             // 16
    const int cols = in_sizes[1] / OG;     // 64
    const int IN   = G * cols * 4;         // 4096
    const int M    = in_sizes[0] / IN;     // 4096

    const int gk = IN / G;                 // 256
    int gshift = 0;
    while ((1 << gshift) < gk) ++gshift;   // 8

    const size_t needA = (size_t)M * IN * 2;
    const size_t needW = (size_t)OUT * IN * 2;

    if (ws_size >= needA + needW && (IN & 7) == 0 &&
        (M % 128) == 0 && (OUT % 128) == 0 && (IN % 64) == 0) {
        u16* wsA = (u16*)d_ws;
        u16* wsW = (u16*)((char*)d_ws + needA);

        const size_t nA8 = (size_t)M * IN / 8;
        cvtA_kernel<<<(unsigned)((nA8 + 255) / 256), 256, 0, stream>>>(A, wsA, nA8);

        int kgshift = 0;
        while ((1 << kgshift) < (IN >> 3)) ++kgshift;
        const size_t nW8 = (size_t)OUT * IN / 8;
        deqW_kernel<<<(unsigned)((nW8 + 255) / 256), 256, 0, stream>>>(
            Wp, Ws, Wb, wsW, IN, G, gshift, kgshift, nW8);

        if ((M % 256) == 0 && (OUT % 256) == 0) {
            dim3 grid((M / BM2) * (OUT / BN2));
            gql_gemm_256<<<grid, THREADS2, 0, stream>>>(wsA, wsW, Bias, Out,
                                                        M, OUT, IN);
        } else {
            dim3 grid((M / BM) * (OUT / BN));
            gql_gemm_pre<<<grid, THREADS, 0, stream>>>(wsA, wsW, Bias, Out,
                                                       M, OUT, IN);
        }
    } else {
        dim3 grid((M / BM) * (OUT / BN));
        gql_gemm<<<grid, THREADS, 0, stream>>>(A, Wp, Ws, Wb, Bias, Out,
                                               M, OUT, IN, G, gshift);
    }
}